// Round 4
// baseline (314.202 us; speedup 1.0000x reference)
//
#include <hip/hip_runtime.h>
#include <hip/hip_bf16.h>

typedef __attribute__((ext_vector_type(8))) short bf16x8;
typedef __attribute__((ext_vector_type(4))) float f32x4;
typedef __attribute__((ext_vector_type(8))) unsigned short u16x8;
typedef __attribute__((ext_vector_type(4))) unsigned short u16x4;

#define BN_EPS 1e-5f

__device__ __forceinline__ unsigned short f2bf(float f) {
  unsigned int u = __float_as_uint(f);
  unsigned int r = u + 0x7FFFu + ((u >> 16) & 1u);
  return (unsigned short)(r >> 16);
}
__device__ __forceinline__ float bf2f(unsigned short u) {
  union { float f; unsigned int i; } v; v.i = ((unsigned int)u) << 16; return v.f;
}

// async global->LDS, 16B per lane. LDS dest = wave-uniform base + lane*16.
__device__ __forceinline__ void async_ld16(const unsigned short* g, unsigned short* l) {
  __builtin_amdgcn_global_load_lds(
      (const __attribute__((address_space(1))) void*)g,
      (__attribute__((address_space(3))) void*)l, 16, 0, 0);
}

// ---------------------------------------------------------------------------
// K1: fold scale1 into W1 (bf16, staged layout) + all BN param folding.
// Layout: Bt[tap][chunk(8)][q(4)][cout(256)][8ch] -> conv3x3 B staging is
// lane-contiguous (16 B/lane, 1 KB/instr coalesced).
__global__ __launch_bounds__(256) void fold_w1_kernel(
    const float* __restrict__ W1, const float* __restrict__ g1,
    const float* __restrict__ b1, const float* __restrict__ m1,
    const float* __restrict__ v1, const float* __restrict__ W2,
    const float* __restrict__ g2, const float* __restrict__ b2,
    const float* __restrict__ m2, const float* __restrict__ v2,
    unsigned short* __restrict__ Bt, float* __restrict__ bias1,
    float* __restrict__ W2f, float* __restrict__ bias2)
{
  int o = blockIdx.x;           // cout 0..255
  int t = threadIdx.x;          // cin 0..255
  if (o == 0) {                 // merged params work (once)
    float s1 = g1[t] * rsqrtf(v1[t] + BN_EPS);
    bias1[t] = b1[t] - m1[t] * s1;
    for (int i = t; i < 2304; i += 256) {
      int j = i >> 8;
      float s2 = g2[j] * rsqrtf(v2[j] + BN_EPS);
      W2f[i] = W2[i] * s2;
    }
    if (t < 9) {
      float s2 = g2[t] * rsqrtf(v2[t] + BN_EPS);
      bias2[t] = b2[t] - m2[t] * s2;
    }
  }
  float s = g1[o] * rsqrtf(v1[o] + BN_EPS);
  const float* src = W1 + (size_t)o * 2304 + (size_t)t * 9;   // W1[o][cin][tap]
  int chunk = t >> 5, q = (t >> 3) & 3, e = t & 7;
  #pragma unroll
  for (int tap = 0; tap < 9; ++tap) {
    float wv = src[tap] * s;
    Bt[((((size_t)tap * 8 + chunk) * 4 + q) * 256 + o) * 8 + e] = f2bf(wv);
  }
}

// ---------------------------------------------------------------------------
// K2: y (fp32 NCHW) -> zero-padded bf16 yTp[n][qg(32)][hh][ww][8ch]
// Border zeroing merged. Write mapping: w fastest across lanes -> 512 B
// contiguous per 32-lane group (was 16 B per plane-scattered lane-octet).
__global__ __launch_bounds__(256) void transpose_pad_kernel(
    const float* __restrict__ y, unsigned short* __restrict__ yTp)
{
  __shared__ unsigned short T[64][68];   // [c_local][w]
  int t = threadIdx.x;
  int nb = blockIdx.x; int n = nb >> 6, h = nb & 63;
  int w4 = (t & 15) * 4;
  int cl = t >> 4;
  for (int cb = 0; cb < 4; ++cb) {
    __syncthreads();
    #pragma unroll
    for (int r = 0; r < 4; ++r) {
      int c = cb * 64 + cl + r * 16;
      float4 v = *(const float4*)(y + ((((size_t)n * 256 + c) * 64 + h) << 6) + w4);
      u16x4 pv = { f2bf(v.x), f2bf(v.y), f2bf(v.z), f2bf(v.w) };
      *(u16x4*)&T[cl + r * 16][w4] = pv;
    }
    __syncthreads();
    size_t base = ((((size_t)n * 32 + cb * 8) * 66 + (h + 1)) * 66 + 1) * 8;
    #pragma unroll
    for (int pass = 0; pass < 2; ++pass) {
      int w = (t & 31) + pass * 32;     // lanes contiguous in w
      int c8 = t >> 5;                  // plane per 32-lane group
      u16x8 o;
      #pragma unroll
      for (int i = 0; i < 8; ++i) o[i] = T[c8 * 8 + i][w];
      *(u16x8*)(yTp + base + ((size_t)c8 * (66 * 66) + w) * 8) = o;
    }
  }
  // ---- merged border zeroing (global, disjoint, no sync needed) ----
  u16x8 z = (u16x8){0, 0, 0, 0, 0, 0, 0, 0};
  size_t nb32 = (size_t)n * 32;
  if (t < 64) {                       // cols ww=0 / ww=65 of row h+1, 32 planes
    int qg = t & 31, side = t >> 5;
    *(u16x8*)(yTp + (((nb32 + qg) * 66 + (h + 1)) * 66 + side * 65) * 8) = z;
  }
  if (h == 0) {                       // rows hh=0 and hh=65, all planes/cols
    for (int i = t; i < 2112; i += 256) {   // 32 planes * 66 cols
      int qg = i / 66, ww = i - qg * 66;
      *(u16x8*)(yTp + (((nb32 + qg) * 66 + 0) * 66 + ww) * 8) = z;
      *(u16x8*)(yTp + (((nb32 + qg) * 66 + 65) * 66 + ww) * 8) = z;
    }
  }
}

// ---------------------------------------------------------------------------
// K3: conv3x3 implicit GEMM + FUSED 1x1 conv epilogue.
// Main loop = round-2 proven structure EXACTLY (runtime tap indices,
// #pragma unroll 1, barrier-then-stage; branches pin the VMEM issue order --
// full unroll let the scheduler sink the stages into the next barrier's
// vmcnt(0) drain, costing +47 us). No setprio (neutral-negative on lockstep).
__global__ __launch_bounds__(256, 2) void conv3x3_mfma_kernel(
    const unsigned short* __restrict__ yTp, const unsigned short* __restrict__ Bt,
    const float* __restrict__ bias1, const float* __restrict__ a1p,
    const float* __restrict__ W2f, const float* __restrict__ bias2,
    const float* __restrict__ a2p, float* __restrict__ kernP)
{
  __shared__ union SM {
    struct { unsigned short A[2][4][4][66][8];      // 33792 B
             unsigned short B[2][4][256][8]; } m;   // 32768 B
    unsigned short h[128][264];                     // 67584 B (overlay)
  } sm;
  __shared__ float w2s[2304];

  int tid = threadIdx.x;
  int w = tid >> 6, l = tid & 63;
  int lr = l & 15, quad = l >> 4;
  int wm = w >> 1, wn = w & 1;                 // 2x2 waves over (M=128, N=256)
  int bm = blockIdx.x;                         // 0..511
  int n = bm >> 5, hb = (bm & 31) * 2;

  for (int i = tid; i < 2304; i += 256) w2s[i] = W2f[i];

  f32x4 acc[4][8];
  #pragma unroll
  for (int im = 0; im < 4; ++im)
    #pragma unroll
    for (int in_ = 0; in_ < 8; ++in_)
      acc[im][in_] = (f32x4){0.f, 0.f, 0.f, 0.f};

  const unsigned short* gaBase = yTp + (size_t)n * 32 * (66 * 66 * 8);

  auto stageA = [&](int chunk, int buf) {
    int qg0 = chunk * 4;
    #pragma unroll
    for (int q = 0; q < 4; ++q) {
      const unsigned short* ga = gaBase +
          (((size_t)(qg0 + q) * 66 + (hb + w)) * 66 + l) * 8;
      async_ld16(ga, &sm.m.A[buf][q][w][0][0]);
    }
    if (l < 2) {  // px 64,65 tail: 2-lane exec-masked async, still contiguous
      #pragma unroll
      for (int q = 0; q < 4; ++q) {
        const unsigned short* ga = gaBase +
            (((size_t)(qg0 + q) * 66 + (hb + w)) * 66 + 64 + l) * 8;
        async_ld16(ga, &sm.m.A[buf][q][w][64][0]);
      }
    }
  };
  auto stageB = [&](int tap, int chunk, int buf) {
    #pragma unroll
    for (int q = 0; q < 4; ++q) {
      const unsigned short* gb = Bt +
          ((((size_t)tap * 8 + chunk) * 4 + q) * 256 + w * 64 + l) * 8;
      async_ld16(gb, &sm.m.B[buf][q][w * 64][0]);
    }
  };

  // prologue: stage (chunk0, tap0); first barrier drains it (once, uncovered)
  stageA(0, 0);
  stageB(0, 0, 0);

  int ab = 0, bb = 0;
  #pragma unroll 1
  for (int c = 0; c < 8; ++c) {
    #pragma unroll 1
    for (int t = 0; t < 9; ++t) {
      __syncthreads();   // drains stage issued LAST iter (full compute cover);
                         // also: all waves done reading buf^1 -> safe to overwrite
      if (t < 8) stageB(t + 1, c, bb ^ 1);
      else if (c < 7) stageB(0, c + 1, bb ^ 1);
      if (t == 0 && c < 7) stageA(c + 1, ab ^ 1);

      int ti = t / 3, tj = t - 3 * ti;
      bf16x8 af[4], bfr[8];
      #pragma unroll
      for (int im = 0; im < 4; ++im)
        af[im] = *(const bf16x8*)&sm.m.A[ab][quad][wm + ti][im * 16 + lr + tj][0];
      #pragma unroll
      for (int in_ = 0; in_ < 8; ++in_)
        bfr[in_] = *(const bf16x8*)&sm.m.B[bb][quad][wn * 128 + in_ * 16 + lr][0];
      #pragma unroll
      for (int im = 0; im < 4; ++im)
        #pragma unroll
        for (int in_ = 0; in_ < 8; ++in_)
          acc[im][in_] = __builtin_amdgcn_mfma_f32_16x16x32_bf16(
              af[im], bfr[in_], acc[im][in_], 0, 0, 0);

      bb ^= 1;
    }
    ab ^= 1;
  }

  __syncthreads();            // all staging-buffer reads done -> overlay safe

  // epilogue 1: h = prelu(acc + bias1) -> LDS bf16 tile [pixel][channel]
  float a1 = a1p[0];
  #pragma unroll
  for (int in_ = 0; in_ < 8; ++in_) {
    int cch = wn * 128 + in_ * 16 + lr;
    float bs = bias1[cch];
    #pragma unroll
    for (int im = 0; im < 4; ++im) {
      int p0 = wm * 64 + im * 16 + quad * 4;
      #pragma unroll
      for (int r = 0; r < 4; ++r) {
        float v = acc[im][in_][r] + bs;
        v = (v >= 0.f) ? v : a1 * v;
        sm.h[p0 + r][cch] = f2bf(v);
      }
    }
  }
  __syncthreads();

  // epilogue 2: 1x1 conv C->9 + BN + PReLU, block-local (4 lanes/pixel)
  float a2 = a2p[0];
  int seg = tid & 3, pr = tid >> 2;
  float b2r[9];
  #pragma unroll
  for (int j = 0; j < 9; ++j) b2r[j] = bias2[j];
  #pragma unroll
  for (int rd = 0; rd < 2; ++rd) {
    int pl = rd * 64 + pr;
    float acc2[9];
    #pragma unroll
    for (int j = 0; j < 9; ++j) acc2[j] = 0.f;
    #pragma unroll
    for (int k = 0; k < 8; ++k) {
      int c0 = seg * 8 + k * 32;
      u16x8 hv = *(const u16x8*)&sm.h[pl][c0];
      float hf[8];
      #pragma unroll
      for (int i = 0; i < 8; ++i) hf[i] = bf2f(hv[i]);
      #pragma unroll
      for (int j = 0; j < 9; ++j)
        #pragma unroll
        for (int i = 0; i < 8; ++i)
          acc2[j] = fmaf(hf[i], w2s[j * 256 + c0 + i], acc2[j]);
    }
    #pragma unroll
    for (int j = 0; j < 9; ++j) {
      acc2[j] += __shfl_xor(acc2[j], 1);
      acc2[j] += __shfl_xor(acc2[j], 2);
    }
    if (seg == 0) {
      size_t gp = (size_t)bm * 128 + pl;
      #pragma unroll
      for (int j = 0; j < 9; ++j) {
        float v = acc2[j] + b2r[j];
        v = (v >= 0.f) ? v : a2 * v;
        kernP[j * 65536 + gp] = v;
      }
    }
  }
}

// ---------------------------------------------------------------------------
// K5: scrambled unfold-reshape apply: consecutive-r walk over a padded
// 66x67 LDS plane (addr++, +3 fixup every 64, one plane-crossing fixup).
__global__ __launch_bounds__(256) void apply_dyn_kernel(
    const float* __restrict__ x, const float* __restrict__ kernP,
    float* __restrict__ out)
{
  __shared__ float xs[66 * 67];   // padded plane, row stride 67
  __shared__ float ks[9][16];
  int t = threadIdx.x;
  int b = blockIdx.x;             // ((n*64 + h')*4 + g)
  int g = b & 3;
  int nh = b >> 2;
  int n = nh >> 6, hp = nh & 63;
  int c = 4 * hp + g;

  const float* xplane = x + (((size_t)n * 256 + c) << 12);
  for (int i = t; i < 1024; i += 256) {
    float4 v = *(const float4*)(xplane + i * 4);
    int row = i >> 4;
    int col = (i & 15) * 4;
    float* d = &xs[(row + 1) * 67 + col + 1];
    d[0] = v.x; d[1] = v.y; d[2] = v.z; d[3] = v.w;
  }
  if (t < 67) { xs[t] = 0.f; xs[65 * 67 + t] = 0.f; }
  if (t < 128) { int r = (t >> 1) + 1; int cc = (t & 1) * 65; xs[r * 67 + cc] = 0.f; }
  int pbase = n * 4096 + hp * 64 + g * 16;
  for (int i = t; i < 144; i += 256)
    ks[i / 16][i & 15] = kernP[(i / 16) * 65536 + pbase + (i & 15)];
  __syncthreads();

  int s = t & 15;
  int crow = t >> 4;              // 0..15; this thread: cp = crow*16 + oi
  float ksr[9];
  #pragma unroll
  for (int k2 = 0; k2 < 9; ++k2) ksr[k2] = ks[k2][s];

  int r0 = s * 2304 + crow * 144;
  int k0 = r0 >> 12;
  int rem0 = r0 & 4095;
  int wcol = rem0 & 63;
  int ti0 = (k0 >= 6) ? 2 : ((k0 >= 3) ? 1 : 0);
  int tj0 = k0 - 3 * ti0;
  int addr = (rem0 >> 6) * 67 + wcol + ti0 * 67 + tj0;
  int cnt = 4096 - rem0;
  int kN = k0 + 1;
  int tiN = (kN >= 6) ? 2 : ((kN >= 3) ? 1 : 0);
  int addrAtCross = tiN * 67 + (kN - 3 * tiN);

  size_t outIdx = (((size_t)n * 256 + crow * 16) << 12) + (hp << 6) + g * 16 + s;
  #pragma unroll 4
  for (int oi = 0; oi < 16; ++oi) {
    float acc = 0.f;
    #pragma unroll
    for (int k2 = 0; k2 < 9; ++k2) {
      acc = fmaf(xs[addr], ksr[k2], acc);
      ++wcol; ++addr;
      if (wcol == 64) { wcol = 0; addr += 3; }
      if (--cnt == 0) addr = addrAtCross;
    }
    out[outIdx + ((size_t)oi << 12)] = acc;
  }
}

// ---------------------------------------------------------------------------
extern "C" void kernel_launch(void* const* d_in, const int* in_sizes, int n_in,
                              void* d_out, int out_size, void* d_ws, size_t ws_size,
                              hipStream_t stream) {
  const float* x  = (const float*)d_in[0];
  const float* y  = (const float*)d_in[1];
  const float* W1 = (const float*)d_in[2];
  const float* g1 = (const float*)d_in[3];
  const float* b1 = (const float*)d_in[4];
  const float* m1 = (const float*)d_in[5];
  const float* v1 = (const float*)d_in[6];
  const float* a1 = (const float*)d_in[7];
  const float* W2 = (const float*)d_in[8];
  const float* g2 = (const float*)d_in[9];
  const float* b2 = (const float*)d_in[10];
  const float* m2 = (const float*)d_in[11];
  const float* v2 = (const float*)d_in[12];
  const float* a2 = (const float*)d_in[13];
  float* out = (float*)d_out;

  char* ws = (char*)d_ws;
  size_t off = 0;
  const size_t yTp_bytes = (size_t)16 * 66 * 66 * 256 * 2;
  unsigned short* yTp = (unsigned short*)(ws + off); off += yTp_bytes;
  unsigned short* Bt  = (unsigned short*)(ws + off); off += (size_t)589824 * 2;
  float* kernP = (float*)(ws + off); off += (size_t)589824 * 4;
  float* bias1 = (float*)(ws + off); off += 1024;
  float* W2f   = (float*)(ws + off); off += 9216;
  float* bias2 = (float*)(ws + off); off += 64;

  fold_w1_kernel<<<256, 256, 0, stream>>>(W1, g1, b1, m1, v1, W2, g2, b2, m2, v2,
                                          Bt, bias1, W2f, bias2);
  transpose_pad_kernel<<<1024, 256, 0, stream>>>(y, yTp);
  conv3x3_mfma_kernel<<<512, 256, 0, stream>>>(yTp, Bt, bias1, a1,
                                               W2f, bias2, a2, kernP);
  apply_dyn_kernel<<<4096, 256, 0, stream>>>(x, kernP, out);
}

// Round 5
// 313.260 us; speedup vs baseline: 1.0030x; 1.0030x over previous
//
#include <hip/hip_runtime.h>
#include <hip/hip_bf16.h>

typedef __attribute__((ext_vector_type(8))) short bf16x8;
typedef __attribute__((ext_vector_type(4))) float f32x4;
typedef __attribute__((ext_vector_type(8))) unsigned short u16x8;
typedef __attribute__((ext_vector_type(4))) unsigned short u16x4;

#define BN_EPS 1e-5f

__device__ __forceinline__ unsigned short f2bf(float f) {
  unsigned int u = __float_as_uint(f);
  unsigned int r = u + 0x7FFFu + ((u >> 16) & 1u);
  return (unsigned short)(r >> 16);
}
__device__ __forceinline__ float bf2f(unsigned short u) {
  union { float f; unsigned int i; } v; v.i = ((unsigned int)u) << 16; return v.f;
}

// async global->LDS, 16B per lane. LDS dest = wave-uniform base + lane*16.
__device__ __forceinline__ void async_ld16(const unsigned short* g, unsigned short* l) {
  __builtin_amdgcn_global_load_lds(
      (const __attribute__((address_space(1))) void*)g,
      (__attribute__((address_space(3))) void*)l, 16, 0, 0);
}

// ---------------------------------------------------------------------------
// K1: fold scale1 into W1 (bf16, staged layout) + all BN param folding.
// Layout: Bt[chunk(8)][tap(9)][q(4)][cout(256)][8ch] -- slab order ==
// conv3x3 consumption order (chunk-major), so staging walks a single
// incremented pointer. Per-instr lane-contiguity (16 B/lane) preserved.
__global__ __launch_bounds__(256) void fold_w1_kernel(
    const float* __restrict__ W1, const float* __restrict__ g1,
    const float* __restrict__ b1, const float* __restrict__ m1,
    const float* __restrict__ v1, const float* __restrict__ W2,
    const float* __restrict__ g2, const float* __restrict__ b2,
    const float* __restrict__ m2, const float* __restrict__ v2,
    unsigned short* __restrict__ Bt, float* __restrict__ bias1,
    float* __restrict__ W2f, float* __restrict__ bias2)
{
  int o = blockIdx.x;           // cout 0..255
  int t = threadIdx.x;          // cin 0..255
  if (o == 0) {                 // merged params work (once)
    float s1 = g1[t] * rsqrtf(v1[t] + BN_EPS);
    bias1[t] = b1[t] - m1[t] * s1;
    for (int i = t; i < 2304; i += 256) {
      int j = i >> 8;
      float s2 = g2[j] * rsqrtf(v2[j] + BN_EPS);
      W2f[i] = W2[i] * s2;
    }
    if (t < 9) {
      float s2 = g2[t] * rsqrtf(v2[t] + BN_EPS);
      bias2[t] = b2[t] - m2[t] * s2;
    }
  }
  float s = g1[o] * rsqrtf(v1[o] + BN_EPS);
  const float* src = W1 + (size_t)o * 2304 + (size_t)t * 9;   // W1[o][cin][tap]
  int chunk = t >> 5, q = (t >> 3) & 3, e = t & 7;
  #pragma unroll
  for (int tap = 0; tap < 9; ++tap) {
    float wv = src[tap] * s;
    int ct = chunk * 9 + tap;
    Bt[(((size_t)ct * 4 + q) * 256 + o) * 8 + e] = f2bf(wv);
  }
}

// ---------------------------------------------------------------------------
// K2: y (fp32 NCHW) -> zero-padded bf16 yTp[n][qg(32)][hh][ww][8ch]
// Border zeroing merged. Write mapping = round-3 measured-good pattern
// (c8 = t&7 fastest; the r4 "w fastest" variant cost +44 us in rest-time).
__global__ __launch_bounds__(256) void transpose_pad_kernel(
    const float* __restrict__ y, unsigned short* __restrict__ yTp)
{
  __shared__ unsigned short T[64][68];   // [c_local][w]
  int t = threadIdx.x;
  int nb = blockIdx.x; int n = nb >> 6, h = nb & 63;
  int w4 = (t & 15) * 4;
  int cl = t >> 4;
  for (int cb = 0; cb < 4; ++cb) {
    __syncthreads();
    #pragma unroll
    for (int r = 0; r < 4; ++r) {
      int c = cb * 64 + cl + r * 16;
      float4 v = *(const float4*)(y + ((((size_t)n * 256 + c) * 64 + h) << 6) + w4);
      u16x4 pv = { f2bf(v.x), f2bf(v.y), f2bf(v.z), f2bf(v.w) };
      *(u16x4*)&T[cl + r * 16][w4] = pv;
    }
    __syncthreads();
    size_t base = ((((size_t)n * 32 + cb * 8) * 66 + (h + 1)) * 66 + 1) * 8;
    #pragma unroll
    for (int pass = 0; pass < 2; ++pass) {
      int w = pass * 32 + (t >> 3);
      int c8 = t & 7;
      u16x8 o;
      #pragma unroll
      for (int i = 0; i < 8; ++i) o[i] = T[c8 * 8 + i][w];
      *(u16x8*)(yTp + base + ((size_t)c8 * (66 * 66) + w) * 8) = o;
    }
  }
  // ---- merged border zeroing (global, disjoint, no sync needed) ----
  u16x8 z = (u16x8){0, 0, 0, 0, 0, 0, 0, 0};
  size_t nb32 = (size_t)n * 32;
  if (t < 64) {                       // cols ww=0 / ww=65 of row h+1, 32 planes
    int qg = t & 31, side = t >> 5;
    *(u16x8*)(yTp + (((nb32 + qg) * 66 + (h + 1)) * 66 + side * 65) * 8) = z;
  }
  if (h == 0) {                       // rows hh=0 and hh=65, all planes/cols
    for (int i = t; i < 2112; i += 256) {   // 32 planes * 66 cols
      int qg = i / 66, ww = i - qg * 66;
      *(u16x8*)(yTp + (((nb32 + qg) * 66 + 0) * 66 + ww) * 8) = z;
      *(u16x8*)(yTp + (((nb32 + qg) * 66 + 65) * 66 + ww) * 8) = z;
    }
  }
}

// ---------------------------------------------------------------------------
// K3: conv3x3 implicit GEMM + FUSED 1x1 conv epilogue.
// Main loop = round-2 proven structure (runtime tap indices, #pragma unroll 1,
// barrier-then-stage). Staging addresses are now running pointers (Bt slab
// order == consumption order) -> no per-iteration 64-bit addr recompute.
__global__ __launch_bounds__(256, 2) void conv3x3_mfma_kernel(
    const unsigned short* __restrict__ yTp, const unsigned short* __restrict__ Bt,
    const float* __restrict__ bias1, const float* __restrict__ a1p,
    const float* __restrict__ W2f, const float* __restrict__ bias2,
    const float* __restrict__ a2p, float* __restrict__ kernP)
{
  __shared__ union SM {
    struct { unsigned short A[2][4][4][66][8];      // 33792 B
             unsigned short B[2][4][256][8]; } m;   // 32768 B
    unsigned short h[128][264];                     // 67584 B (overlay)
  } sm;
  __shared__ float w2s[2304];

  int tid = threadIdx.x;
  int w = tid >> 6, l = tid & 63;
  int lr = l & 15, quad = l >> 4;
  int wm = w >> 1, wn = w & 1;                 // 2x2 waves over (M=128, N=256)
  int bm = blockIdx.x;                         // 0..511
  int n = bm >> 5, hb = (bm & 31) * 2;

  for (int i = tid; i < 2304; i += 256) w2s[i] = W2f[i];

  f32x4 acc[4][8];
  #pragma unroll
  for (int im = 0; im < 4; ++im)
    #pragma unroll
    for (int in_ = 0; in_ < 8; ++in_)
      acc[im][in_] = (f32x4){0.f, 0.f, 0.f, 0.f};

  // running per-lane staging pointers (u16 units)
  const unsigned short* gaP =
      yTp + (((size_t)n * 32 * 66 + (hb + w)) * 66 + l) * 8;
  const unsigned short* gbP = Bt + (size_t)(w * 64 + l) * 8;

  auto stageA = [&](int buf) {
    async_ld16(gaP,          &sm.m.A[buf][0][w][0][0]);
    async_ld16(gaP + 34848,  &sm.m.A[buf][1][w][0][0]);
    async_ld16(gaP + 69696,  &sm.m.A[buf][2][w][0][0]);
    async_ld16(gaP + 104544, &sm.m.A[buf][3][w][0][0]);
    if (l < 2) {  // px 64,65 tail: 2-lane exec-masked async
      async_ld16(gaP + 512,          &sm.m.A[buf][0][w][64][0]);
      async_ld16(gaP + 34848 + 512,  &sm.m.A[buf][1][w][64][0]);
      async_ld16(gaP + 69696 + 512,  &sm.m.A[buf][2][w][64][0]);
      async_ld16(gaP + 104544 + 512, &sm.m.A[buf][3][w][64][0]);
    }
    gaP += 139392;            // next chunk (4 planes)
  };
  auto stageB = [&](int buf) {
    async_ld16(gbP,        &sm.m.B[buf][0][w * 64][0]);
    async_ld16(gbP + 2048, &sm.m.B[buf][1][w * 64][0]);
    async_ld16(gbP + 4096, &sm.m.B[buf][2][w * 64][0]);
    async_ld16(gbP + 6144, &sm.m.B[buf][3][w * 64][0]);
    gbP += 8192;              // next (chunk,tap) slab
  };

  // prologue: stage (chunk0, tap0); first barrier drains it (once, uncovered)
  stageA(0);
  stageB(0);

  int ab = 0, bb = 0;
  #pragma unroll 1
  for (int c = 0; c < 8; ++c) {
    #pragma unroll 1
    for (int t = 0; t < 9; ++t) {
      __syncthreads();   // drains stage issued LAST iter (full compute cover);
                         // also: all waves done reading buf^1 -> safe to overwrite
      if (t < 8 || c < 7) stageB(bb ^ 1);      // next slab (sequential gbP)
      if (t == 0 && c < 7) stageA(ab ^ 1);

      int ti = t / 3, tj = t - 3 * ti;
      bf16x8 af[4], bfr[8];
      #pragma unroll
      for (int im = 0; im < 4; ++im)
        af[im] = *(const bf16x8*)&sm.m.A[ab][quad][wm + ti][im * 16 + lr + tj][0];
      #pragma unroll
      for (int in_ = 0; in_ < 8; ++in_)
        bfr[in_] = *(const bf16x8*)&sm.m.B[bb][quad][wn * 128 + in_ * 16 + lr][0];
      #pragma unroll
      for (int im = 0; im < 4; ++im)
        #pragma unroll
        for (int in_ = 0; in_ < 8; ++in_)
          acc[im][in_] = __builtin_amdgcn_mfma_f32_16x16x32_bf16(
              af[im], bfr[in_], acc[im][in_], 0, 0, 0);

      bb ^= 1;
    }
    ab ^= 1;
  }

  __syncthreads();            // all staging-buffer reads done -> overlay safe

  // epilogue 1: h = prelu(acc + bias1) -> LDS bf16 tile [pixel][channel]
  float a1 = a1p[0];
  #pragma unroll
  for (int in_ = 0; in_ < 8; ++in_) {
    int cch = wn * 128 + in_ * 16 + lr;
    float bs = bias1[cch];
    #pragma unroll
    for (int im = 0; im < 4; ++im) {
      int p0 = wm * 64 + im * 16 + quad * 4;
      #pragma unroll
      for (int r = 0; r < 4; ++r) {
        float v = acc[im][in_][r] + bs;
        v = (v >= 0.f) ? v : a1 * v;
        sm.h[p0 + r][cch] = f2bf(v);
      }
    }
  }
  __syncthreads();

  // epilogue 2: 1x1 conv C->9 + BN + PReLU, block-local (4 lanes/pixel)
  float a2 = a2p[0];
  int seg = tid & 3, pr = tid >> 2;
  float b2r[9];
  #pragma unroll
  for (int j = 0; j < 9; ++j) b2r[j] = bias2[j];
  #pragma unroll
  for (int rd = 0; rd < 2; ++rd) {
    int pl = rd * 64 + pr;
    float acc2[9];
    #pragma unroll
    for (int j = 0; j < 9; ++j) acc2[j] = 0.f;
    #pragma unroll
    for (int k = 0; k < 8; ++k) {
      int c0 = seg * 8 + k * 32;
      u16x8 hv = *(const u16x8*)&sm.h[pl][c0];
      float hf[8];
      #pragma unroll
      for (int i = 0; i < 8; ++i) hf[i] = bf2f(hv[i]);
      #pragma unroll
      for (int j = 0; j < 9; ++j)
        #pragma unroll
        for (int i = 0; i < 8; ++i)
          acc2[j] = fmaf(hf[i], w2s[j * 256 + c0 + i], acc2[j]);
    }
    #pragma unroll
    for (int j = 0; j < 9; ++j) {
      acc2[j] += __shfl_xor(acc2[j], 1);
      acc2[j] += __shfl_xor(acc2[j], 2);
    }
    if (seg == 0) {
      size_t gp = (size_t)bm * 128 + pl;
      #pragma unroll
      for (int j = 0; j < 9; ++j) {
        float v = acc2[j] + b2r[j];
        v = (v >= 0.f) ? v : a2 * v;
        kernP[j * 65536 + gp] = v;
      }
    }
  }
}

// ---------------------------------------------------------------------------
// K5: scrambled unfold-reshape apply: consecutive-r walk over a padded
// 66x67 LDS plane (addr++, +3 fixup every 64, one plane-crossing fixup).
__global__ __launch_bounds__(256) void apply_dyn_kernel(
    const float* __restrict__ x, const float* __restrict__ kernP,
    float* __restrict__ out)
{
  __shared__ float xs[66 * 67];   // padded plane, row stride 67
  __shared__ float ks[9][16];
  int t = threadIdx.x;
  int b = blockIdx.x;             // ((n*64 + h')*4 + g)
  int g = b & 3;
  int nh = b >> 2;
  int n = nh >> 6, hp = nh & 63;
  int c = 4 * hp + g;

  const float* xplane = x + (((size_t)n * 256 + c) << 12);
  for (int i = t; i < 1024; i += 256) {
    float4 v = *(const float4*)(xplane + i * 4);
    int row = i >> 4;
    int col = (i & 15) * 4;
    float* d = &xs[(row + 1) * 67 + col + 1];
    d[0] = v.x; d[1] = v.y; d[2] = v.z; d[3] = v.w;
  }
  if (t < 67) { xs[t] = 0.f; xs[65 * 67 + t] = 0.f; }
  if (t < 128) { int r = (t >> 1) + 1; int cc = (t & 1) * 65; xs[r * 67 + cc] = 0.f; }
  int pbase = n * 4096 + hp * 64 + g * 16;
  for (int i = t; i < 144; i += 256)
    ks[i / 16][i & 15] = kernP[(i / 16) * 65536 + pbase + (i & 15)];
  __syncthreads();

  int s = t & 15;
  int crow = t >> 4;              // 0..15; this thread: cp = crow*16 + oi
  float ksr[9];
  #pragma unroll
  for (int k2 = 0; k2 < 9; ++k2) ksr[k2] = ks[k2][s];

  int r0 = s * 2304 + crow * 144;
  int k0 = r0 >> 12;
  int rem0 = r0 & 4095;
  int wcol = rem0 & 63;
  int ti0 = (k0 >= 6) ? 2 : ((k0 >= 3) ? 1 : 0);
  int tj0 = k0 - 3 * ti0;
  int addr = (rem0 >> 6) * 67 + wcol + ti0 * 67 + tj0;
  int cnt = 4096 - rem0;
  int kN = k0 + 1;
  int tiN = (kN >= 6) ? 2 : ((kN >= 3) ? 1 : 0);
  int addrAtCross = tiN * 67 + (kN - 3 * tiN);

  size_t outIdx = (((size_t)n * 256 + crow * 16) << 12) + (hp << 6) + g * 16 + s;
  #pragma unroll 4
  for (int oi = 0; oi < 16; ++oi) {
    float acc = 0.f;
    #pragma unroll
    for (int k2 = 0; k2 < 9; ++k2) {
      acc = fmaf(xs[addr], ksr[k2], acc);
      ++wcol; ++addr;
      if (wcol == 64) { wcol = 0; addr += 3; }
      if (--cnt == 0) addr = addrAtCross;
    }
    out[outIdx + ((size_t)oi << 12)] = acc;
  }
}

// ---------------------------------------------------------------------------
extern "C" void kernel_launch(void* const* d_in, const int* in_sizes, int n_in,
                              void* d_out, int out_size, void* d_ws, size_t ws_size,
                              hipStream_t stream) {
  const float* x  = (const float*)d_in[0];
  const float* y  = (const float*)d_in[1];
  const float* W1 = (const float*)d_in[2];
  const float* g1 = (const float*)d_in[3];
  const float* b1 = (const float*)d_in[4];
  const float* m1 = (const float*)d_in[5];
  const float* v1 = (const float*)d_in[6];
  const float* a1 = (const float*)d_in[7];
  const float* W2 = (const float*)d_in[8];
  const float* g2 = (const float*)d_in[9];
  const float* b2 = (const float*)d_in[10];
  const float* m2 = (const float*)d_in[11];
  const float* v2 = (const float*)d_in[12];
  const float* a2 = (const float*)d_in[13];
  float* out = (float*)d_out;

  char* ws = (char*)d_ws;
  size_t off = 0;
  const size_t yTp_bytes = (size_t)16 * 66 * 66 * 256 * 2;
  unsigned short* yTp = (unsigned short*)(ws + off); off += yTp_bytes;
  unsigned short* Bt  = (unsigned short*)(ws + off); off += (size_t)589824 * 2;
  float* kernP = (float*)(ws + off); off += (size_t)589824 * 4;
  float* bias1 = (float*)(ws + off); off += 1024;
  float* W2f   = (float*)(ws + off); off += 9216;
  float* bias2 = (float*)(ws + off); off += 64;

  fold_w1_kernel<<<256, 256, 0, stream>>>(W1, g1, b1, m1, v1, W2, g2, b2, m2, v2,
                                          Bt, bias1, W2f, bias2);
  transpose_pad_kernel<<<1024, 256, 0, stream>>>(y, yTp);
  conv3x3_mfma_kernel<<<512, 256, 0, stream>>>(yTp, Bt, bias1, a1,
                                               W2f, bias2, a2, kernP);
  apply_dyn_kernel<<<4096, 256, 0, stream>>>(x, kernP, out);
}

// Round 6
// 307.330 us; speedup vs baseline: 1.0224x; 1.0193x over previous
//
#include <hip/hip_runtime.h>
#include <hip/hip_bf16.h>

typedef __attribute__((ext_vector_type(8))) short bf16x8;
typedef __attribute__((ext_vector_type(4))) float f32x4;
typedef __attribute__((ext_vector_type(8))) unsigned short u16x8;
typedef __attribute__((ext_vector_type(4))) unsigned short u16x4;

#define BN_EPS 1e-5f

__device__ __forceinline__ unsigned short f2bf(float f) {
  unsigned int u = __float_as_uint(f);
  unsigned int r = u + 0x7FFFu + ((u >> 16) & 1u);
  return (unsigned short)(r >> 16);
}
__device__ __forceinline__ float bf2f(unsigned short u) {
  union { float f; unsigned int i; } v; v.i = ((unsigned int)u) << 16; return v.f;
}

// async global->LDS, 16B per lane. LDS dest = wave-uniform base + lane*16.
__device__ __forceinline__ void async_ld16(const unsigned short* g, unsigned short* l) {
  __builtin_amdgcn_global_load_lds(
      (const __attribute__((address_space(1))) void*)g,
      (__attribute__((address_space(3))) void*)l, 16, 0, 0);
}

// ---------------------------------------------------------------------------
// K1: fold scale1 into W1 (bf16, staged layout) + all BN param folding.
// Layout: Bt[chunk(8)][tap(9)][q(4)][cout(256)][8ch] -- slab order ==
// conv3x3 consumption order; conv3x3 B-loads are per-lane 16B contiguous.
__global__ __launch_bounds__(256) void fold_w1_kernel(
    const float* __restrict__ W1, const float* __restrict__ g1,
    const float* __restrict__ b1, const float* __restrict__ m1,
    const float* __restrict__ v1, const float* __restrict__ W2,
    const float* __restrict__ g2, const float* __restrict__ b2,
    const float* __restrict__ m2, const float* __restrict__ v2,
    unsigned short* __restrict__ Bt, float* __restrict__ bias1,
    float* __restrict__ W2f, float* __restrict__ bias2)
{
  int o = blockIdx.x;           // cout 0..255
  int t = threadIdx.x;          // cin 0..255
  if (o == 0) {                 // merged params work (once)
    float s1 = g1[t] * rsqrtf(v1[t] + BN_EPS);
    bias1[t] = b1[t] - m1[t] * s1;
    for (int i = t; i < 2304; i += 256) {
      int j = i >> 8;
      float s2 = g2[j] * rsqrtf(v2[j] + BN_EPS);
      W2f[i] = W2[i] * s2;
    }
    if (t < 9) {
      float s2 = g2[t] * rsqrtf(v2[t] + BN_EPS);
      bias2[t] = b2[t] - m2[t] * s2;
    }
  }
  float s = g1[o] * rsqrtf(v1[o] + BN_EPS);
  const float* src = W1 + (size_t)o * 2304 + (size_t)t * 9;   // W1[o][cin][tap]
  int chunk = t >> 5, q = (t >> 3) & 3, e = t & 7;
  #pragma unroll
  for (int tap = 0; tap < 9; ++tap) {
    float wv = src[tap] * s;
    int ct = chunk * 9 + tap;
    Bt[(((size_t)ct * 4 + q) * 256 + o) * 8 + e] = f2bf(wv);
  }
}

// ---------------------------------------------------------------------------
// K2: y (fp32 NCHW) -> zero-padded bf16 yTp[n][qg(32)][hh][ww][8ch]
// Border zeroing merged. (r3-measured write mapping, frozen.)
__global__ __launch_bounds__(256) void transpose_pad_kernel(
    const float* __restrict__ y, unsigned short* __restrict__ yTp)
{
  __shared__ unsigned short T[64][68];   // [c_local][w]
  int t = threadIdx.x;
  int nb = blockIdx.x; int n = nb >> 6, h = nb & 63;
  int w4 = (t & 15) * 4;
  int cl = t >> 4;
  for (int cb = 0; cb < 4; ++cb) {
    __syncthreads();
    #pragma unroll
    for (int r = 0; r < 4; ++r) {
      int c = cb * 64 + cl + r * 16;
      float4 v = *(const float4*)(y + ((((size_t)n * 256 + c) * 64 + h) << 6) + w4);
      u16x4 pv = { f2bf(v.x), f2bf(v.y), f2bf(v.z), f2bf(v.w) };
      *(u16x4*)&T[cl + r * 16][w4] = pv;
    }
    __syncthreads();
    size_t base = ((((size_t)n * 32 + cb * 8) * 66 + (h + 1)) * 66 + 1) * 8;
    #pragma unroll
    for (int pass = 0; pass < 2; ++pass) {
      int w = pass * 32 + (t >> 3);
      int c8 = t & 7;
      u16x8 o;
      #pragma unroll
      for (int i = 0; i < 8; ++i) o[i] = T[c8 * 8 + i][w];
      *(u16x8*)(yTp + base + ((size_t)c8 * (66 * 66) + w) * 8) = o;
    }
  }
  // ---- merged border zeroing (global, disjoint, no sync needed) ----
  u16x8 z = (u16x8){0, 0, 0, 0, 0, 0, 0, 0};
  size_t nb32 = (size_t)n * 32;
  if (t < 64) {                       // cols ww=0 / ww=65 of row h+1, 32 planes
    int qg = t & 31, side = t >> 5;
    *(u16x8*)(yTp + (((nb32 + qg) * 66 + (h + 1)) * 66 + side * 65) * 8) = z;
  }
  if (h == 0) {                       // rows hh=0 and hh=65, all planes/cols
    for (int i = t; i < 2112; i += 256) {   // 32 planes * 66 cols
      int qg = i / 66, ww = i - qg * 66;
      *(u16x8*)(yTp + (((nb32 + qg) * 66 + 0) * 66 + ww) * 8) = z;
      *(u16x8*)(yTp + (((nb32 + qg) * 66 + 65) * 66 + ww) * 8) = z;
    }
  }
}

// ---------------------------------------------------------------------------
// K3: conv3x3 implicit GEMM + FUSED 1x1 conv epilogue.
// NEW: B operand loaded global->VGPR directly (per-lane-private 16B frags,
// L2/L3-resident Bt) with 1-iter register ping-pong (two named sets).
// Only A lives in LDS -> barriers drop 72 -> 8 (one per chunk), and the
// per-CU LDS-read pipe load falls ~3x (was the 4x-oversubscribed pipe).
__global__ __launch_bounds__(256, 2) void conv3x3_mfma_kernel(
    const unsigned short* __restrict__ yTp, const unsigned short* __restrict__ Bt,
    const float* __restrict__ bias1, const float* __restrict__ a1p,
    const float* __restrict__ W2f, const float* __restrict__ bias2,
    const float* __restrict__ a2p, float* __restrict__ kernP)
{
  __shared__ union SM {
    unsigned short A[2][4][4][66][8];               // 33792 B (staging)
    unsigned short h[128][264];                     // 67584 B (overlay)
  } sm;
  __shared__ float w2s[2304];

  int tid = threadIdx.x;
  int w = tid >> 6, l = tid & 63;
  int lr = l & 15, quad = l >> 4;
  int wm = w >> 1, wn = w & 1;                 // 2x2 waves over (M=128, N=256)
  int bm = blockIdx.x;                         // 0..511
  int n = bm >> 5, hb = (bm & 31) * 2;

  for (int i = tid; i < 2304; i += 256) w2s[i] = W2f[i];

  f32x4 acc[4][8];
  #pragma unroll
  for (int im = 0; im < 4; ++im)
    #pragma unroll
    for (int in_ = 0; in_ < 8; ++in_)
      acc[im][in_] = (f32x4){0.f, 0.f, 0.f, 0.f};

  // A staging: running per-lane pointer (u16 units)
  const unsigned short* gaP =
      yTp + (((size_t)n * 32 * 66 + (hb + w)) * 66 + l) * 8;
  auto stageA = [&](int buf) {
    async_ld16(gaP,          &sm.A[buf][0][w][0][0]);
    async_ld16(gaP + 34848,  &sm.A[buf][1][w][0][0]);
    async_ld16(gaP + 69696,  &sm.A[buf][2][w][0][0]);
    async_ld16(gaP + 104544, &sm.A[buf][3][w][0][0]);
    if (l < 2) {  // px 64,65 tail: 2-lane exec-masked async
      async_ld16(gaP + 512,          &sm.A[buf][0][w][64][0]);
      async_ld16(gaP + 34848 + 512,  &sm.A[buf][1][w][64][0]);
      async_ld16(gaP + 69696 + 512,  &sm.A[buf][2][w][64][0]);
      async_ld16(gaP + 104544 + 512, &sm.A[buf][3][w][64][0]);
    }
    gaP += 139392;            // next chunk (4 planes)
  };

  // B direct-to-register: slab tt = chunk*9+tap, per-lane frag offset.
  const unsigned short* gbBase = Bt + (size_t)(quad * 256 + wn * 128 + lr) * 8;
  auto loadB = [&](bf16x8* dst, int tt) {
    const unsigned short* p = gbBase + ((size_t)tt << 13);   // slab stride 8192 u16
    #pragma unroll
    for (int in_ = 0; in_ < 8; ++in_)
      dst[in_] = *(const bf16x8*)(p + in_ * 128);            // 16 couts apart
  };

  auto computeTap = [&](const bf16x8* b, int ab, int tap) {
    int ti = (tap >= 6) ? 2 : ((tap >= 3) ? 1 : 0);
    int tj = tap - 3 * ti;
    bf16x8 af[4];
    #pragma unroll
    for (int im = 0; im < 4; ++im)
      af[im] = *(const bf16x8*)&sm.A[ab][quad][wm + ti][im * 16 + lr + tj][0];
    #pragma unroll
    for (int im = 0; im < 4; ++im)
      #pragma unroll
      for (int in_ = 0; in_ < 8; ++in_)
        acc[im][in_] = __builtin_amdgcn_mfma_f32_16x16x32_bf16(
            af[im], b[in_], acc[im][in_], 0, 0, 0);
  };

  // prologue: stage A chunk0, load B slab 0 into regs
  stageA(0);
  bf16x8 bA[8], bB[8];
  loadB(bA, 0);

  int tap = 0, ab = 0;
  #pragma unroll 1
  for (int tt = 0; tt < 72; tt += 2) {
    // ---- even: consume bA, prefetch bB ----
    if (tap == 0) {                  // chunk start (uniform scalar branch)
      __syncthreads();               // A[ab] landed (all waves); A[ab^1] free
      if (tt < 63) stageA(ab ^ 1);   // DMA next chunk (9 taps of cover)
    }
    loadB(bB, tt + 1);
    computeTap(bA, ab, tap);
    if (++tap == 9) { tap = 0; ab ^= 1; }
    // ---- odd: consume bB, prefetch bA ----
    if (tap == 0) {
      __syncthreads();
      if (tt + 1 < 63) stageA(ab ^ 1);
    }
    if (tt + 2 < 72) loadB(bA, tt + 2);
    computeTap(bB, ab, tap);
    if (++tap == 9) { tap = 0; ab ^= 1; }
  }

  __syncthreads();            // all A reads done -> h overlay safe

  // epilogue 1: h = prelu(acc + bias1) -> LDS bf16 tile [pixel][channel]
  float a1 = a1p[0];
  #pragma unroll
  for (int in_ = 0; in_ < 8; ++in_) {
    int cch = wn * 128 + in_ * 16 + lr;
    float bs = bias1[cch];
    #pragma unroll
    for (int im = 0; im < 4; ++im) {
      int p0 = wm * 64 + im * 16 + quad * 4;
      #pragma unroll
      for (int r = 0; r < 4; ++r) {
        float v = acc[im][in_][r] + bs;
        v = (v >= 0.f) ? v : a1 * v;
        sm.h[p0 + r][cch] = f2bf(v);
      }
    }
  }
  __syncthreads();

  // epilogue 2: 1x1 conv C->9 + BN + PReLU, block-local (4 lanes/pixel)
  float a2 = a2p[0];
  int seg = tid & 3, pr = tid >> 2;
  float b2r[9];
  #pragma unroll
  for (int j = 0; j < 9; ++j) b2r[j] = bias2[j];
  #pragma unroll
  for (int rd = 0; rd < 2; ++rd) {
    int pl = rd * 64 + pr;
    float acc2[9];
    #pragma unroll
    for (int j = 0; j < 9; ++j) acc2[j] = 0.f;
    #pragma unroll
    for (int k = 0; k < 8; ++k) {
      int c0 = seg * 8 + k * 32;
      u16x8 hv = *(const u16x8*)&sm.h[pl][c0];
      float hf[8];
      #pragma unroll
      for (int i = 0; i < 8; ++i) hf[i] = bf2f(hv[i]);
      #pragma unroll
      for (int j = 0; j < 9; ++j)
        #pragma unroll
        for (int i = 0; i < 8; ++i)
          acc2[j] = fmaf(hf[i], w2s[j * 256 + c0 + i], acc2[j]);
    }
    #pragma unroll
    for (int j = 0; j < 9; ++j) {
      acc2[j] += __shfl_xor(acc2[j], 1);
      acc2[j] += __shfl_xor(acc2[j], 2);
    }
    if (seg == 0) {
      size_t gp = (size_t)bm * 128 + pl;
      #pragma unroll
      for (int j = 0; j < 9; ++j) {
        float v = acc2[j] + b2r[j];
        v = (v >= 0.f) ? v : a2 * v;
        kernP[j * 65536 + gp] = v;
      }
    }
  }
}

// ---------------------------------------------------------------------------
// K5: scrambled unfold-reshape apply: consecutive-r walk over a padded
// 66x67 LDS plane (addr++, +3 fixup every 64, one plane-crossing fixup).
__global__ __launch_bounds__(256) void apply_dyn_kernel(
    const float* __restrict__ x, const float* __restrict__ kernP,
    float* __restrict__ out)
{
  __shared__ float xs[66 * 67];   // padded plane, row stride 67
  __shared__ float ks[9][16];
  int t = threadIdx.x;
  int b = blockIdx.x;             // ((n*64 + h')*4 + g)
  int g = b & 3;
  int nh = b >> 2;
  int n = nh >> 6, hp = nh & 63;
  int c = 4 * hp + g;

  const float* xplane = x + (((size_t)n * 256 + c) << 12);
  for (int i = t; i < 1024; i += 256) {
    float4 v = *(const float4*)(xplane + i * 4);
    int row = i >> 4;
    int col = (i & 15) * 4;
    float* d = &xs[(row + 1) * 67 + col + 1];
    d[0] = v.x; d[1] = v.y; d[2] = v.z; d[3] = v.w;
  }
  if (t < 67) { xs[t] = 0.f; xs[65 * 67 + t] = 0.f; }
  if (t < 128) { int r = (t >> 1) + 1; int cc = (t & 1) * 65; xs[r * 67 + cc] = 0.f; }
  int pbase = n * 4096 + hp * 64 + g * 16;
  for (int i = t; i < 144; i += 256)
    ks[i / 16][i & 15] = kernP[(i / 16) * 65536 + pbase + (i & 15)];
  __syncthreads();

  int s = t & 15;
  int crow = t >> 4;              // 0..15; this thread: cp = crow*16 + oi
  float ksr[9];
  #pragma unroll
  for (int k2 = 0; k2 < 9; ++k2) ksr[k2] = ks[k2][s];

  int r0 = s * 2304 + crow * 144;
  int k0 = r0 >> 12;
  int rem0 = r0 & 4095;
  int wcol = rem0 & 63;
  int ti0 = (k0 >= 6) ? 2 : ((k0 >= 3) ? 1 : 0);
  int tj0 = k0 - 3 * ti0;
  int addr = (rem0 >> 6) * 67 + wcol + ti0 * 67 + tj0;
  int cnt = 4096 - rem0;
  int kN = k0 + 1;
  int tiN = (kN >= 6) ? 2 : ((kN >= 3) ? 1 : 0);
  int addrAtCross = tiN * 67 + (kN - 3 * tiN);

  size_t outIdx = (((size_t)n * 256 + crow * 16) << 12) + (hp << 6) + g * 16 + s;
  #pragma unroll 4
  for (int oi = 0; oi < 16; ++oi) {
    float acc = 0.f;
    #pragma unroll
    for (int k2 = 0; k2 < 9; ++k2) {
      acc = fmaf(xs[addr], ksr[k2], acc);
      ++wcol; ++addr;
      if (wcol == 64) { wcol = 0; addr += 3; }
      if (--cnt == 0) addr = addrAtCross;
    }
    out[outIdx + ((size_t)oi << 12)] = acc;
  }
}

// ---------------------------------------------------------------------------
extern "C" void kernel_launch(void* const* d_in, const int* in_sizes, int n_in,
                              void* d_out, int out_size, void* d_ws, size_t ws_size,
                              hipStream_t stream) {
  const float* x  = (const float*)d_in[0];
  const float* y  = (const float*)d_in[1];
  const float* W1 = (const float*)d_in[2];
  const float* g1 = (const float*)d_in[3];
  const float* b1 = (const float*)d_in[4];
  const float* m1 = (const float*)d_in[5];
  const float* v1 = (const float*)d_in[6];
  const float* a1 = (const float*)d_in[7];
  const float* W2 = (const float*)d_in[8];
  const float* g2 = (const float*)d_in[9];
  const float* b2 = (const float*)d_in[10];
  const float* m2 = (const float*)d_in[11];
  const float* v2 = (const float*)d_in[12];
  const float* a2 = (const float*)d_in[13];
  float* out = (float*)d_out;

  char* ws = (char*)d_ws;
  size_t off = 0;
  const size_t yTp_bytes = (size_t)16 * 66 * 66 * 256 * 2;
  unsigned short* yTp = (unsigned short*)(ws + off); off += yTp_bytes;
  unsigned short* Bt  = (unsigned short*)(ws + off); off += (size_t)589824 * 2;
  float* kernP = (float*)(ws + off); off += (size_t)589824 * 4;
  float* bias1 = (float*)(ws + off); off += 1024;
  float* W2f   = (float*)(ws + off); off += 9216;
  float* bias2 = (float*)(ws + off); off += 64;

  fold_w1_kernel<<<256, 256, 0, stream>>>(W1, g1, b1, m1, v1, W2, g2, b2, m2, v2,
                                          Bt, bias1, W2f, bias2);
  transpose_pad_kernel<<<1024, 256, 0, stream>>>(y, yTp);
  conv3x3_mfma_kernel<<<512, 256, 0, stream>>>(yTp, Bt, bias1, a1,
                                               W2f, bias2, a2, kernP);
  apply_dyn_kernel<<<4096, 256, 0, stream>>>(x, kernP, out);
}

// Round 7
// 303.199 us; speedup vs baseline: 1.0363x; 1.0136x over previous
//
#include <hip/hip_runtime.h>
#include <hip/hip_bf16.h>

typedef __attribute__((ext_vector_type(8))) short bf16x8;
typedef __attribute__((ext_vector_type(4))) float f32x4;
typedef __attribute__((ext_vector_type(8))) unsigned short u16x8;
typedef __attribute__((ext_vector_type(4))) unsigned short u16x4;

#define BN_EPS 1e-5f

__device__ __forceinline__ unsigned short f2bf(float f) {
  unsigned int u = __float_as_uint(f);
  unsigned int r = u + 0x7FFFu + ((u >> 16) & 1u);
  return (unsigned short)(r >> 16);
}
__device__ __forceinline__ float bf2f(unsigned short u) {
  union { float f; unsigned int i; } v; v.i = ((unsigned int)u) << 16; return v.f;
}

// async global->LDS, 16B per lane. LDS dest = wave-uniform base + lane*16.
__device__ __forceinline__ void async_ld16(const unsigned short* g, unsigned short* l) {
  __builtin_amdgcn_global_load_lds(
      (const __attribute__((address_space(1))) void*)g,
      (__attribute__((address_space(3))) void*)l, 16, 0, 0);
}

// ---------------------------------------------------------------------------
// K1: fold scale1 into W1 (bf16, staged layout) + all BN param folding.
// Layout: Bt[chunk(8)][tap(9)][q(4)][cout(256)][8ch].
__global__ __launch_bounds__(256) void fold_w1_kernel(
    const float* __restrict__ W1, const float* __restrict__ g1,
    const float* __restrict__ b1, const float* __restrict__ m1,
    const float* __restrict__ v1, const float* __restrict__ W2,
    const float* __restrict__ g2, const float* __restrict__ b2,
    const float* __restrict__ m2, const float* __restrict__ v2,
    unsigned short* __restrict__ Bt, float* __restrict__ bias1,
    float* __restrict__ W2f, float* __restrict__ bias2)
{
  int o = blockIdx.x;           // cout 0..255
  int t = threadIdx.x;          // cin 0..255
  if (o == 0) {                 // merged params work (once)
    float s1 = g1[t] * rsqrtf(v1[t] + BN_EPS);
    bias1[t] = b1[t] - m1[t] * s1;
    for (int i = t; i < 2304; i += 256) {
      int j = i >> 8;
      float s2 = g2[j] * rsqrtf(v2[j] + BN_EPS);
      W2f[i] = W2[i] * s2;
    }
    if (t < 9) {
      float s2 = g2[t] * rsqrtf(v2[t] + BN_EPS);
      bias2[t] = b2[t] - m2[t] * s2;
    }
  }
  float s = g1[o] * rsqrtf(v1[o] + BN_EPS);
  const float* src = W1 + (size_t)o * 2304 + (size_t)t * 9;   // W1[o][cin][tap]
  int chunk = t >> 5, q = (t >> 3) & 3, e = t & 7;
  #pragma unroll
  for (int tap = 0; tap < 9; ++tap) {
    float wv = src[tap] * s;
    int ct = chunk * 9 + tap;
    Bt[(((size_t)ct * 4 + q) * 256 + o) * 8 + e] = f2bf(wv);
  }
}

// ---------------------------------------------------------------------------
// K2: y (fp32 NCHW) -> zero-padded bf16 yTp[n][qg(32)][hh][ww][8ch]
// Border zeroing merged. (r3-measured write mapping, frozen.)
__global__ __launch_bounds__(256) void transpose_pad_kernel(
    const float* __restrict__ y, unsigned short* __restrict__ yTp)
{
  __shared__ unsigned short T[64][68];   // [c_local][w]
  int t = threadIdx.x;
  int nb = blockIdx.x; int n = nb >> 6, h = nb & 63;
  int w4 = (t & 15) * 4;
  int cl = t >> 4;
  for (int cb = 0; cb < 4; ++cb) {
    __syncthreads();
    #pragma unroll
    for (int r = 0; r < 4; ++r) {
      int c = cb * 64 + cl + r * 16;
      float4 v = *(const float4*)(y + ((((size_t)n * 256 + c) * 64 + h) << 6) + w4);
      u16x4 pv = { f2bf(v.x), f2bf(v.y), f2bf(v.z), f2bf(v.w) };
      *(u16x4*)&T[cl + r * 16][w4] = pv;
    }
    __syncthreads();
    size_t base = ((((size_t)n * 32 + cb * 8) * 66 + (h + 1)) * 66 + 1) * 8;
    #pragma unroll
    for (int pass = 0; pass < 2; ++pass) {
      int w = pass * 32 + (t >> 3);
      int c8 = t & 7;
      u16x8 o;
      #pragma unroll
      for (int i = 0; i < 8; ++i) o[i] = T[c8 * 8 + i][w];
      *(u16x8*)(yTp + base + ((size_t)c8 * (66 * 66) + w) * 8) = o;
    }
  }
  // ---- merged border zeroing (global, disjoint, no sync needed) ----
  u16x8 z = (u16x8){0, 0, 0, 0, 0, 0, 0, 0};
  size_t nb32 = (size_t)n * 32;
  if (t < 64) {                       // cols ww=0 / ww=65 of row h+1, 32 planes
    int qg = t & 31, side = t >> 5;
    *(u16x8*)(yTp + (((nb32 + qg) * 66 + (h + 1)) * 66 + side * 65) * 8) = z;
  }
  if (h == 0) {                       // rows hh=0 and hh=65, all planes/cols
    for (int i = t; i < 2112; i += 256) {   // 32 planes * 66 cols
      int qg = i / 66, ww = i - qg * 66;
      *(u16x8*)(yTp + (((nb32 + qg) * 66 + 0) * 66 + ww) * 8) = z;
      *(u16x8*)(yTp + (((nb32 + qg) * 66 + 65) * 66 + ww) * 8) = z;
    }
  }
}

// ---------------------------------------------------------------------------
// K3: conv3x3 implicit GEMM + FUSED 1x1 conv epilogue.
// Wave geometry 1x4 over cout: each wave = ALL 128 px x 64 couts.
// B duplication 2x -> 1x (B-L1 traffic halved: was the binding pipe at
// ~1024 cyc/CU-tap); A-LDS rises to 768 cyc but LDS is the faster pipe.
// Ping-pong B-in-regs schedule and all staging kept from r6 (proven).
__global__ __launch_bounds__(256, 2) void conv3x3_mfma_kernel(
    const unsigned short* __restrict__ yTp, const unsigned short* __restrict__ Bt,
    const float* __restrict__ bias1, const float* __restrict__ a1p,
    const float* __restrict__ W2f, const float* __restrict__ bias2,
    const float* __restrict__ a2p, float* __restrict__ kernP)
{
  __shared__ union SM {
    unsigned short A[2][4][4][66][8];               // 33792 B (staging)
    unsigned short h[128][264];                     // 67584 B (overlay)
  } sm;
  __shared__ float w2s[2304];

  int tid = threadIdx.x;
  int w = tid >> 6, l = tid & 63;                // w = cout-group AND stage-row
  int lr = l & 15, quad = l >> 4;
  int bm = blockIdx.x;                           // 0..511
  int n = bm >> 5, hb = (bm & 31) * 2;

  for (int i = tid; i < 2304; i += 256) w2s[i] = W2f[i];

  f32x4 acc[8][4];
  #pragma unroll
  for (int im = 0; im < 8; ++im)
    #pragma unroll
    for (int in_ = 0; in_ < 4; ++in_)
      acc[im][in_] = (f32x4){0.f, 0.f, 0.f, 0.f};

  // A staging: running per-lane pointer (u16 units); wave w stages row hb+w
  const unsigned short* gaP =
      yTp + (((size_t)n * 32 * 66 + (hb + w)) * 66 + l) * 8;
  auto stageA = [&](int buf) {
    async_ld16(gaP,          &sm.A[buf][0][w][0][0]);
    async_ld16(gaP + 34848,  &sm.A[buf][1][w][0][0]);
    async_ld16(gaP + 69696,  &sm.A[buf][2][w][0][0]);
    async_ld16(gaP + 104544, &sm.A[buf][3][w][0][0]);
    if (l < 2) {  // px 64,65 tail: 2-lane exec-masked async
      async_ld16(gaP + 512,          &sm.A[buf][0][w][64][0]);
      async_ld16(gaP + 34848 + 512,  &sm.A[buf][1][w][64][0]);
      async_ld16(gaP + 69696 + 512,  &sm.A[buf][2][w][64][0]);
      async_ld16(gaP + 104544 + 512, &sm.A[buf][3][w][64][0]);
    }
    gaP += 139392;            // next chunk (4 planes)
  };

  // B direct-to-register: wave w owns couts w*64..w*64+63 (no duplication).
  const unsigned short* gbBase = Bt + (size_t)(quad * 256 + w * 64 + lr) * 8;
  auto loadB = [&](bf16x8* dst, int tt) {
    const unsigned short* p = gbBase + ((size_t)tt << 13);   // slab stride 8192 u16
    #pragma unroll
    for (int in_ = 0; in_ < 4; ++in_)
      dst[in_] = *(const bf16x8*)(p + in_ * 128);            // 16 couts apart
  };

  auto computeTap = [&](const bf16x8* b, int ab, int tap) {
    int ti = (tap >= 6) ? 2 : ((tap >= 3) ? 1 : 0);
    int tj = tap - 3 * ti;
    bf16x8 af[8];
    #pragma unroll
    for (int im = 0; im < 8; ++im)
      af[im] = *(const bf16x8*)
          &sm.A[ab][quad][(im >> 2) + ti][(im & 3) * 16 + lr + tj][0];
    #pragma unroll
    for (int im = 0; im < 8; ++im)
      #pragma unroll
      for (int in_ = 0; in_ < 4; ++in_)
        acc[im][in_] = __builtin_amdgcn_mfma_f32_16x16x32_bf16(
            af[im], b[in_], acc[im][in_], 0, 0, 0);
  };

  // prologue: stage A chunk0, load B slab 0 into regs
  stageA(0);
  bf16x8 bA[4], bB[4];
  loadB(bA, 0);

  int tap = 0, ab = 0;
  #pragma unroll 1
  for (int tt = 0; tt < 72; tt += 2) {
    // ---- even: consume bA, prefetch bB ----
    if (tap == 0) __syncthreads();       // A[ab] landed; A[ab^1] free
    loadB(bB, tt + 1);                   // issue B BEFORE stageA -> B-waits
    if (tap == 0 && tt < 63)             //   never force-drain the A-DMA
      stageA(ab ^ 1);
    computeTap(bA, ab, tap);
    if (++tap == 9) { tap = 0; ab ^= 1; }
    // ---- odd: consume bB, prefetch bA ----
    if (tap == 0) __syncthreads();
    if (tt + 2 < 72) loadB(bA, tt + 2);
    if (tap == 0 && tt + 1 < 63) stageA(ab ^ 1);
    computeTap(bB, ab, tap);
    if (++tap == 9) { tap = 0; ab ^= 1; }
  }

  __syncthreads();            // all A reads done -> h overlay safe

  // epilogue 1: h = prelu(acc + bias1) -> LDS bf16 tile [pixel][channel]
  float a1 = a1p[0];
  #pragma unroll
  for (int in_ = 0; in_ < 4; ++in_) {
    int cch = w * 64 + in_ * 16 + lr;
    float bs = bias1[cch];
    #pragma unroll
    for (int im = 0; im < 8; ++im) {
      int p0 = im * 16 + quad * 4;
      #pragma unroll
      for (int r = 0; r < 4; ++r) {
        float v = acc[im][in_][r] + bs;
        v = (v >= 0.f) ? v : a1 * v;
        sm.h[p0 + r][cch] = f2bf(v);
      }
    }
  }
  __syncthreads();

  // epilogue 2: 1x1 conv C->9 + BN + PReLU, block-local (4 lanes/pixel)
  float a2 = a2p[0];
  int seg = tid & 3, pr = tid >> 2;
  float b2r[9];
  #pragma unroll
  for (int j = 0; j < 9; ++j) b2r[j] = bias2[j];
  #pragma unroll
  for (int rd = 0; rd < 2; ++rd) {
    int pl = rd * 64 + pr;
    float acc2[9];
    #pragma unroll
    for (int j = 0; j < 9; ++j) acc2[j] = 0.f;
    #pragma unroll
    for (int k = 0; k < 8; ++k) {
      int c0 = seg * 8 + k * 32;
      u16x8 hv = *(const u16x8*)&sm.h[pl][c0];
      float hf[8];
      #pragma unroll
      for (int i = 0; i < 8; ++i) hf[i] = bf2f(hv[i]);
      #pragma unroll
      for (int j = 0; j < 9; ++j)
        #pragma unroll
        for (int i = 0; i < 8; ++i)
          acc2[j] = fmaf(hf[i], w2s[j * 256 + c0 + i], acc2[j]);
    }
    #pragma unroll
    for (int j = 0; j < 9; ++j) {
      acc2[j] += __shfl_xor(acc2[j], 1);
      acc2[j] += __shfl_xor(acc2[j], 2);
    }
    if (seg == 0) {
      size_t gp = (size_t)bm * 128 + pl;
      #pragma unroll
      for (int j = 0; j < 9; ++j) {
        float v = acc2[j] + b2r[j];
        v = (v >= 0.f) ? v : a2 * v;
        kernP[j * 65536 + gp] = v;
      }
    }
  }
}

// ---------------------------------------------------------------------------
// K5: scrambled unfold-reshape apply: consecutive-r walk over a padded
// 66x67 LDS plane (addr++, +3 fixup every 64, one plane-crossing fixup).
__global__ __launch_bounds__(256) void apply_dyn_kernel(
    const float* __restrict__ x, const float* __restrict__ kernP,
    float* __restrict__ out)
{
  __shared__ float xs[66 * 67];   // padded plane, row stride 67
  __shared__ float ks[9][16];
  int t = threadIdx.x;
  int b = blockIdx.x;             // ((n*64 + h')*4 + g)
  int g = b & 3;
  int nh = b >> 2;
  int n = nh >> 6, hp = nh & 63;
  int c = 4 * hp + g;

  const float* xplane = x + (((size_t)n * 256 + c) << 12);
  for (int i = t; i < 1024; i += 256) {
    float4 v = *(const float4*)(xplane + i * 4);
    int row = i >> 4;
    int col = (i & 15) * 4;
    float* d = &xs[(row + 1) * 67 + col + 1];
    d[0] = v.x; d[1] = v.y; d[2] = v.z; d[3] = v.w;
  }
  if (t < 67) { xs[t] = 0.f; xs[65 * 67 + t] = 0.f; }
  if (t < 128) { int r = (t >> 1) + 1; int cc = (t & 1) * 65; xs[r * 67 + cc] = 0.f; }
  int pbase = n * 4096 + hp * 64 + g * 16;
  for (int i = t; i < 144; i += 256)
    ks[i / 16][i & 15] = kernP[(i / 16) * 65536 + pbase + (i & 15)];
  __syncthreads();

  int s = t & 15;
  int crow = t >> 4;              // 0..15; this thread: cp = crow*16 + oi
  float ksr[9];
  #pragma unroll
  for (int k2 = 0; k2 < 9; ++k2) ksr[k2] = ks[k2][s];

  int r0 = s * 2304 + crow * 144;
  int k0 = r0 >> 12;
  int rem0 = r0 & 4095;
  int wcol = rem0 & 63;
  int ti0 = (k0 >= 6) ? 2 : ((k0 >= 3) ? 1 : 0);
  int tj0 = k0 - 3 * ti0;
  int addr = (rem0 >> 6) * 67 + wcol + ti0 * 67 + tj0;
  int cnt = 4096 - rem0;
  int kN = k0 + 1;
  int tiN = (kN >= 6) ? 2 : ((kN >= 3) ? 1 : 0);
  int addrAtCross = tiN * 67 + (kN - 3 * tiN);

  size_t outIdx = (((size_t)n * 256 + crow * 16) << 12) + (hp << 6) + g * 16 + s;
  #pragma unroll 4
  for (int oi = 0; oi < 16; ++oi) {
    float acc = 0.f;
    #pragma unroll
    for (int k2 = 0; k2 < 9; ++k2) {
      acc = fmaf(xs[addr], ksr[k2], acc);
      ++wcol; ++addr;
      if (wcol == 64) { wcol = 0; addr += 3; }
      if (--cnt == 0) addr = addrAtCross;
    }
    out[outIdx + ((size_t)oi << 12)] = acc;
  }
}

// ---------------------------------------------------------------------------
extern "C" void kernel_launch(void* const* d_in, const int* in_sizes, int n_in,
                              void* d_out, int out_size, void* d_ws, size_t ws_size,
                              hipStream_t stream) {
  const float* x  = (const float*)d_in[0];
  const float* y  = (const float*)d_in[1];
  const float* W1 = (const float*)d_in[2];
  const float* g1 = (const float*)d_in[3];
  const float* b1 = (const float*)d_in[4];
  const float* m1 = (const float*)d_in[5];
  const float* v1 = (const float*)d_in[6];
  const float* a1 = (const float*)d_in[7];
  const float* W2 = (const float*)d_in[8];
  const float* g2 = (const float*)d_in[9];
  const float* b2 = (const float*)d_in[10];
  const float* m2 = (const float*)d_in[11];
  const float* v2 = (const float*)d_in[12];
  const float* a2 = (const float*)d_in[13];
  float* out = (float*)d_out;

  char* ws = (char*)d_ws;
  size_t off = 0;
  const size_t yTp_bytes = (size_t)16 * 66 * 66 * 256 * 2;
  unsigned short* yTp = (unsigned short*)(ws + off); off += yTp_bytes;
  unsigned short* Bt  = (unsigned short*)(ws + off); off += (size_t)589824 * 2;
  float* kernP = (float*)(ws + off); off += (size_t)589824 * 4;
  float* bias1 = (float*)(ws + off); off += 1024;
  float* W2f   = (float*)(ws + off); off += 9216;
  float* bias2 = (float*)(ws + off); off += 64;

  fold_w1_kernel<<<256, 256, 0, stream>>>(W1, g1, b1, m1, v1, W2, g2, b2, m2, v2,
                                          Bt, bias1, W2f, bias2);
  transpose_pad_kernel<<<1024, 256, 0, stream>>>(y, yTp);
  conv3x3_mfma_kernel<<<512, 256, 0, stream>>>(yTp, Bt, bias1, a1,
                                               W2f, bias2, a2, kernP);
  apply_dyn_kernel<<<4096, 256, 0, stream>>>(x, kernP, out);
}